// Round 1
// baseline (310.018 us; speedup 1.0000x reference)
//
#include <hip/hip_runtime.h>
#include <stdint.h>

#define NS 64     // N_msa (s)
#define NT 384    // N_tok (i, j)
#define CM 64     // c_m
#define CH 32     // c_h
#define CZ 128    // c_z

typedef __attribute__((ext_vector_type(8))) short bf16x8;
typedef __attribute__((ext_vector_type(16))) float f32x16;

// round-to-nearest-even f32 -> bf16 bits
static __device__ __forceinline__ uint16_t f2bf(float f) {
  uint32_t u = __float_as_uint(f);
  u = (u + 0x7FFFu + ((u >> 16) & 1u)) >> 16;
  return (uint16_t)u;
}
static __device__ __forceinline__ uint32_t pack2(float lo, float hi) {
  return (uint32_t)f2bf(lo) | ((uint32_t)f2bf(hi) << 16);
}
// LDS bank swizzle: targets byte bits 4..6, sources bits 7..9 (c / k) and 11..13 (pair).
// Involution; preserves 16B-block contiguity (b128 reads) and 8B alignment (b64 writes).
static __device__ __forceinline__ int swz(int x) {
  return x ^ ((((x >> 7) ^ (x >> 11)) & 7) << 4);
}

// ---------------- P1: LayerNorm + projections -> a_t[(i*32+c)*64+s], b_t (bf16) ----------
__global__ __launch_bounds__(256) void k_prep(
    const float* __restrict__ m, const float* __restrict__ mask,
    const float* __restrict__ lnw, const float* __restrict__ lnb,
    const float* __restrict__ w1, const float* __restrict__ w2,
    uint16_t* __restrict__ a_t, uint16_t* __restrict__ b_t) {
  __shared__ float mn[64 * 65];  // pad 65: conflict-free column reads
  const int i = blockIdx.x;
  const int tid = threadIdx.x;
  const int wv = tid >> 6, lane = tid & 63;

  // Phase A: LayerNorm rows (s, i) over CM=64; lane = channel
  const float lw = lnw[lane], lb = lnb[lane];
  for (int s = wv; s < NS; s += 4) {
    float x = m[(s * NT + i) * CM + lane];
    float sum = x, sq = x * x;
#pragma unroll
    for (int off = 32; off; off >>= 1) {
      sum += __shfl_xor(sum, off);
      sq  += __shfl_xor(sq, off);
    }
    float mu = sum * (1.f / 64.f);
    float var = sq * (1.f / 64.f) - mu * mu;
    float rs = 1.f / sqrtf(var + 1e-5f);
    mn[s * 65 + lane] = (x - mu) * rs * lw + lb;
  }
  __syncthreads();

  // Phase B: a[c][s] = sum_m mn[s][m] * w1[c][m];  thread: s = lane, c block = tid>>6
  const int s = lane;
  const int cb = __builtin_amdgcn_readfirstlane(tid >> 6);  // 0..3 -> c = cb*8+k
  float accA[8] = {0, 0, 0, 0, 0, 0, 0, 0};
  float accB[8] = {0, 0, 0, 0, 0, 0, 0, 0};
#pragma unroll 8
  for (int mm = 0; mm < CM; ++mm) {
    float v = mn[s * 65 + mm];
#pragma unroll
    for (int k = 0; k < 8; ++k) {
      accA[k] = fmaf(v, w1[(cb * 8 + k) * CM + mm], accA[k]);  // uniform addr -> s_load
      accB[k] = fmaf(v, w2[(cb * 8 + k) * CM + mm], accB[k]);
    }
  }
  const float msk = mask[s * NT + i];
#pragma unroll
  for (int k = 0; k < 8; ++k) {
    int c = cb * 8 + k;
    a_t[(i * CH + c) * NS + s] = f2bf(accA[k] * msk);
    b_t[(i * CH + c) * NS + s] = f2bf(accB[k] * msk);
  }
}

// ---------------- P2: w_out f32 -> bf16 copy ----------------
__global__ __launch_bounds__(256) void k_cvt(const float* __restrict__ w,
                                             uint16_t* __restrict__ o, int n) {
  int t = blockIdx.x * 256 + threadIdx.x;
  if (t < n) o[t] = f2bf(w[t]);
}

// ---------------- P3: inv_norm[i*384+j] = 1/(sum_s mask[s,i]mask[s,j] + 1e-3) ------------
__global__ __launch_bounds__(256) void k_norm(const float* __restrict__ mask,
                                              float* __restrict__ invn) {
  int t = blockIdx.x * 256 + threadIdx.x;  // 147456
  int i = t / NT, j = t - i * NT;
  float acc = 0.f;
#pragma unroll 8
  for (int s = 0; s < NS; ++s) acc += mask[s * NT + i] * mask[s * NT + j];
  invn[t] = 1.f / (acc + 1e-3f);
}

// ---------------- Main: fused O = a^T b  (per 8x8 (i,j) tile) then out = O @ w_out^T ----
__global__ __launch_bounds__(512, 2) void k_main(
    const uint16_t* __restrict__ a_t, const uint16_t* __restrict__ b_t,
    const uint16_t* __restrict__ w2b, const float* __restrict__ b_out,
    const float* __restrict__ invn, float* __restrict__ out) {
  extern __shared__ char lds[];  // O2[pair 64][k2 1024] bf16 = 128 KB, swizzled
  const int tid = threadIdx.x;
  const int wv = tid >> 6;
  const int lane = tid & 63;
  const int lo5 = lane & 31, hi = lane >> 5;
  const int i0 = blockIdx.x * 8, j0 = blockIdx.y * 8;

  // ---- GEMM1': O[(tj,d)][(ti,c)] = sum_s b_t[(tj,d),s] * a_t[(ti,c),s]
  // wave grid 4(m) x 2(n): wave owns 2 m-tiles x 4 n-tiles of 32x32
  const int wm = wv >> 1, wn = wv & 1;
  f32x16 acc1[2][4];
#pragma unroll
  for (int q = 0; q < 2; ++q)
#pragma unroll
    for (int r = 0; r < 4; ++r) acc1[q][r] = (f32x16){};

  // fragment bases: A from b_t rows (j*32+d), B^T from a_t rows (i*32+c); 16B/lane loads
  const uint16_t* Ab = b_t + ((j0 * CH) + wm * 64 + lo5) * NS + hi * 8;
  const uint16_t* Bb = a_t + ((i0 * CH) + wn * 128 + lo5) * NS + hi * 8;
#pragma unroll
  for (int kk = 0; kk < 4; ++kk) {  // K = 64 in steps of 16
    bf16x8 af[2], bfr[4];
#pragma unroll
    for (int q = 0; q < 2; ++q) af[q] = *(const bf16x8*)(Ab + q * 32 * NS + kk * 16);
#pragma unroll
    for (int r = 0; r < 4; ++r) bfr[r] = *(const bf16x8*)(Bb + r * 32 * NS + kk * 16);
#pragma unroll
    for (int q = 0; q < 2; ++q)
#pragma unroll
      for (int r = 0; r < 4; ++r)
        acc1[q][r] = __builtin_amdgcn_mfma_f32_32x32x16_bf16(af[q], bfr[r], acc1[q][r], 0, 0, 0);
  }

  // ---- write O into LDS as O2[pair][c*32+d] bf16 (pair = tj*8+ti), swizzled b64 stores
  // acc C/D layout (32x32): col = lane&31 (= c), row d = (e&3) + 8*(e>>2) + 4*hi
#pragma unroll
  for (int q = 0; q < 2; ++q) {
#pragma unroll
    for (int r = 0; r < 4; ++r) {
      const int p = (wm * 2 + q) * 8 + (wn * 4 + r);
      const int base = p * 2048 + lo5 * 64 + hi * 8;
#pragma unroll
      for (int g = 0; g < 4; ++g) {
        uint64_t v = (uint64_t)pack2(acc1[q][r][4 * g + 0], acc1[q][r][4 * g + 1]) |
                     ((uint64_t)pack2(acc1[q][r][4 * g + 2], acc1[q][r][4 * g + 3]) << 32);
        *(uint64_t*)(lds + swz(base + g * 16)) = v;
      }
    }
  }
  __syncthreads();

  // ---- GEMM2: out2[pair][z] = sum_k2 O2[pair][k2] * w2b[z][k2];  M=64, N=128, K=1024
  // wave = one 32x32 tile: wp = pair-half, wz = z-tile
  const int wp = wv >> 2;  // 0..1
  const int wz = wv & 3;   // 0..3
  f32x16 acc2 = (f32x16){};
  const uint16_t* Wb = w2b + (wz * 32 + lo5) * 1024 + hi * 8;
  const int abyte0 = (wp * 32 + lo5) * 2048 + hi * 16;
#pragma unroll 8
  for (int kk = 0; kk < 64; ++kk) {  // K steps of 16
    bf16x8 a2 = *(const bf16x8*)(lds + swz(abyte0 + kk * 32));
    bf16x8 b2 = *(const bf16x8*)(Wb + kk * 16);
    acc2 = __builtin_amdgcn_mfma_f32_32x32x16_bf16(a2, b2, acc2, 0, 0, 0);
  }

  // ---- epilogue: out[i,j,z] = (acc + b_out[z]) * invn[i,j]
  const int z = wz * 32 + lo5;
  const float bo = b_out[z];
#pragma unroll
  for (int e = 0; e < 16; ++e) {
    int p = wp * 32 + (e & 3) + 8 * (e >> 2) + 4 * hi;  // pair = tj*8+ti
    int ti = p & 7, tj = p >> 3;
    int n = (i0 + ti) * NT + (j0 + tj);
    out[n * CZ + z] = (acc2[e] + bo) * invn[n];
  }
}

extern "C" void kernel_launch(void* const* d_in, const int* in_sizes, int n_in,
                              void* d_out, int out_size, void* d_ws, size_t ws_size,
                              hipStream_t stream) {
  const float* m    = (const float*)d_in[0];
  const float* mask = (const float*)d_in[1];
  const float* lnw  = (const float*)d_in[2];
  const float* lnb  = (const float*)d_in[3];
  const float* w1   = (const float*)d_in[4];
  const float* w2   = (const float*)d_in[5];
  const float* wout = (const float*)d_in[6];
  const float* bout = (const float*)d_in[7];
  float* out = (float*)d_out;

  char* ws = (char*)d_ws;
  uint16_t* a_t = (uint16_t*)ws;                                  // 1.5 MB
  uint16_t* b_t = (uint16_t*)(ws + 1572864);                      // 1.5 MB
  uint16_t* w2b = (uint16_t*)(ws + 2 * 1572864);                  // 256 KB
  float* invn   = (float*)(ws + 2 * 1572864 + 262144);            // 576 KB

  k_prep<<<NT, 256, 0, stream>>>(m, mask, lnw, lnb, w1, w2, a_t, b_t);
  k_cvt<<<512, 256, 0, stream>>>(wout, w2b, CZ * CH * CH);
  k_norm<<<576, 256, 0, stream>>>(mask, invn);

  (void)hipFuncSetAttribute(reinterpret_cast<const void*>(k_main),
                            hipFuncAttributeMaxDynamicSharedMemorySize, 131072);
  k_main<<<dim3(NT / 8, NT / 8), 512, 131072, stream>>>(a_t, b_t, w2b, bout, invn, out);
}

// Round 2
// 193.591 us; speedup vs baseline: 1.6014x; 1.6014x over previous
//
#include <hip/hip_runtime.h>
#include <stdint.h>

#define NS 64     // N_msa (s)
#define NT 384    // N_tok (i, j)
#define CM 64     // c_m
#define CH 32     // c_h
#define CZ 128    // c_z

typedef __attribute__((ext_vector_type(8))) short bf16x8;
typedef __attribute__((ext_vector_type(16))) float f32x16;
typedef __attribute__((ext_vector_type(4))) float f32x4;

// round-to-nearest-even f32 -> bf16 bits
static __device__ __forceinline__ uint16_t f2bf(float f) {
  uint32_t u = __float_as_uint(f);
  u = (u + 0x7FFFu + ((u >> 16) & 1u)) >> 16;
  return (uint16_t)u;
}
static __device__ __forceinline__ uint32_t pack2(float lo, float hi) {
  return (uint32_t)f2bf(lo) | ((uint32_t)f2bf(hi) << 16);
}
// LDS bank swizzle for the O2 buffer (validated in round 1):
// targets byte bits 4..6, sources bits 7..9 (c/k) ^ bits 11..13 (pair).
static __device__ __forceinline__ int swz(int x) {
  return x ^ ((((x >> 7) ^ (x >> 11)) & 7) << 4);
}

// ---- P1: LayerNorm + projections -> fragment-major AF/BF -------------------
// AF[rt=384][kk=4][lane=64][e=8], lane=(hi,lo5): element = a_row[rt*32+lo5][kk*16+hi*8+e]
__global__ __launch_bounds__(256) void k_prep(
    const float* __restrict__ m, const float* __restrict__ mask,
    const float* __restrict__ lnw, const float* __restrict__ lnb,
    const float* __restrict__ w1, const float* __restrict__ w2,
    uint16_t* __restrict__ AF, uint16_t* __restrict__ BF) {
  __shared__ float mn[64 * 65];        // pad 65: conflict-free column reads
  __shared__ float wsh[2][64 * 64];    // staged w1, w2 (32 KB)
  const int i = blockIdx.x;
  const int tid = threadIdx.x;
  const int wv = tid >> 6, lane = tid & 63;

  for (int t = tid; t < 64 * 64; t += 256) {
    wsh[0][t] = w1[t];
    wsh[1][t] = w2[t];
  }

  // Phase A: LayerNorm rows (s, i) over CM=64; lane = channel
  const float lw = lnw[lane], lb = lnb[lane];
  for (int s = wv; s < NS; s += 4) {
    float x = m[(s * NT + i) * CM + lane];
    float sum = x, sq = x * x;
#pragma unroll
    for (int off = 32; off; off >>= 1) {
      sum += __shfl_xor(sum, off);
      sq  += __shfl_xor(sq, off);
    }
    float mu = sum * (1.f / 64.f);
    float var = sq * (1.f / 64.f) - mu * mu;
    float rs = 1.f / sqrtf(var + 1e-5f);
    mn[s * 65 + lane] = (x - mu) * rs * lw + lb;
  }
  __syncthreads();

  // Phase B: a[c][s] = sum_m mn[s][m] * w1[c][m];  thread: s = lane, c = cb*8+k
  const int s = lane;
  const int cb = __builtin_amdgcn_readfirstlane(tid >> 6);  // 0..3
  float accA[8] = {0, 0, 0, 0, 0, 0, 0, 0};
  float accB[8] = {0, 0, 0, 0, 0, 0, 0, 0};
#pragma unroll 8
  for (int mm = 0; mm < CM; ++mm) {
    float v = mn[s * 65 + mm];
#pragma unroll
    for (int k = 0; k < 8; ++k) {
      accA[k] = fmaf(v, wsh[0][(cb * 8 + k) * CM + mm], accA[k]);
      accB[k] = fmaf(v, wsh[1][(cb * 8 + k) * CM + mm], accB[k]);
    }
  }
  const float msk = mask[s * NT + i];
  const int kkq = s >> 4, hh = (s >> 3) & 1, e = s & 7;
  const size_t base = ((size_t)(i * 4 + kkq) * 64 + hh * 32) * 8 + e;
#pragma unroll
  for (int k = 0; k < 8; ++k) {
    int c = cb * 8 + k;
    AF[base + c * 8] = f2bf(accA[k] * msk);
    BF[base + c * 8] = f2bf(accB[k] * msk);
  }
}

// ---- P2: w_out -> fragment-major bf16 W[kk=64][zt=4][lane=64][8]; + inv_norm -----
__global__ __launch_bounds__(256) void k_misc(
    const float* __restrict__ wout, const float* __restrict__ mask,
    uint16_t* __restrict__ W, float* __restrict__ invn) {
  const int b = blockIdx.x;
  if (b < 64) {
    const int g = b * 256 + threadIdx.x;  // 0..16383
    const int l = g & 63, zt = (g >> 6) & 3, kk = g >> 8;
    const float* src = wout + (zt * 32 + (l & 31)) * 1024 + kk * 16 + (l >> 5) * 8;
    uint16_t* dst = W + (size_t)g * 8;
#pragma unroll
    for (int e = 0; e < 8; ++e) dst[e] = f2bf(src[e]);
  } else {
    const int t = (b - 64) * 256 + threadIdx.x;  // 0..147455
    const int i = t / NT, j = t - i * NT;
    float acc = 0.f;
#pragma unroll 8
    for (int s = 0; s < NS; ++s) acc += mask[s * NT + i] * mask[s * NT + j];
    invn[t] = 1.f / (acc + 1e-3f);
  }
}

// ---- Main: fused O = a^T b (8x4 (i,j) tile) then out = O @ w_out^T ---------
// LDS: [0,65536) O2[pair=32][k2=1024] bf16, swizzled; [65536,81920) reduce scratch
__global__ __launch_bounds__(512, 4) void k_main(
    const uint16_t* __restrict__ AF, const uint16_t* __restrict__ BF,
    const uint16_t* __restrict__ W, const float* __restrict__ b_out,
    const float* __restrict__ invn, float* __restrict__ out) {
  extern __shared__ char lds[];
  const int tid = threadIdx.x;
  const int wv = tid >> 6;
  const int l = tid & 63;
  const int lo5 = l & 31, hi = l >> 5;
  const int i0 = blockIdx.x * 8, j0 = blockIdx.y * 4;

  // ---- GEMM1: O[(tj,d)][(ti,c)], M=128 (4 tiles), N=256 (8 tiles), K=64
  // wave (wm, wn): m-tile wm (tj=wm), n-tiles wn*4+r (ti)
  const int wm = wv >> 1, wn = wv & 1;
  f32x16 acc1[4];
#pragma unroll
  for (int r = 0; r < 4; ++r) acc1[r] = (f32x16){};

  const uint16_t* Abase = BF + ((size_t)(j0 + wm) * 4) * 512 + l * 8;
  const uint16_t* Bbase = AF + ((size_t)(i0 + wn * 4) * 4) * 512 + l * 8;
#pragma unroll
  for (int kk = 0; kk < 4; ++kk) {
    bf16x8 af = *(const bf16x8*)(Abase + kk * 512);
    bf16x8 bfr[4];
#pragma unroll
    for (int r = 0; r < 4; ++r) bfr[r] = *(const bf16x8*)(Bbase + (r * 4 + kk) * 512);
#pragma unroll
    for (int r = 0; r < 4; ++r)
      acc1[r] = __builtin_amdgcn_mfma_f32_32x32x16_bf16(af, bfr[r], acc1[r], 0, 0, 0);
  }

  // ---- write O into LDS as O2[pair][c*32+d] bf16 (pair = tj*8+ti)
  // acc C/D layout (32x32): col = lane&31 (= c), row d = (e&3) + 8*(e>>2) + 4*hi
#pragma unroll
  for (int r = 0; r < 4; ++r) {
    const int p = wm * 8 + wn * 4 + r;
    const int base = p * 2048 + lo5 * 64 + hi * 8;
#pragma unroll
    for (int g = 0; g < 4; ++g) {
      uint64_t v = (uint64_t)pack2(acc1[r][4 * g + 0], acc1[r][4 * g + 1]) |
                   ((uint64_t)pack2(acc1[r][4 * g + 2], acc1[r][4 * g + 3]) << 32);
      *(uint64_t*)(lds + swz(base + g * 16)) = v;
    }
  }
  __syncthreads();

  // ---- GEMM2: out2[pair][z] = sum_k2 O2[pair][k2] * W;  M=32, N=128, K=1024
  // wave (wk, wz): K-half wk (512), z-tile wz
  const int wk = wv >> 2, wz = wv & 3;
  f32x16 acc2 = (f32x16){};
  const uint16_t* Wb = W + ((size_t)(wk * 32 * 4 + wz) * 64 + l) * 8;
  const int abyte0 = lo5 * 2048 + wk * 1024 + hi * 16;
#pragma unroll 8
  for (int kk = 0; kk < 32; ++kk) {
    bf16x8 a2 = *(const bf16x8*)(lds + swz(abyte0 + kk * 32));
    bf16x8 b2 = *(const bf16x8*)(Wb + (size_t)kk * 2048);
    acc2 = __builtin_amdgcn_mfma_f32_32x32x16_bf16(a2, b2, acc2, 0, 0, 0);
  }

  // ---- cross-wave K reduction through LDS scratch
  char* scr = lds + 65536;
  if (wk == 1) {
    const int sb = wz * 4096;
#pragma unroll
    for (int g = 0; g < 4; ++g) {
      f32x4 v = {acc2[4 * g + 0], acc2[4 * g + 1], acc2[4 * g + 2], acc2[4 * g + 3]};
      *(f32x4*)(scr + sb + ((l * 64 + g * 16) ^ ((l & 7) << 4))) = v;
    }
  }
  __syncthreads();
  if (wk == 0) {
    const int sb = wz * 4096;
#pragma unroll
    for (int g = 0; g < 4; ++g) {
      f32x4 v = *(const f32x4*)(scr + sb + ((l * 64 + g * 16) ^ ((l & 7) << 4)));
#pragma unroll
      for (int jj = 0; jj < 4; ++jj) acc2[4 * g + jj] += v[jj];
    }
    // ---- epilogue
    const int z = wz * 32 + lo5;
    const float bo = b_out[z];
#pragma unroll
    for (int e = 0; e < 16; ++e) {
      int p = (e & 3) + 8 * (e >> 2) + 4 * hi;  // pair = tj*8+ti
      int ti = p & 7, tj = p >> 3;
      int n = (i0 + ti) * NT + (j0 + tj);
      out[(size_t)n * CZ + z] = (acc2[e] + bo) * invn[n];
    }
  }
}

extern "C" void kernel_launch(void* const* d_in, const int* in_sizes, int n_in,
                              void* d_out, int out_size, void* d_ws, size_t ws_size,
                              hipStream_t stream) {
  const float* m    = (const float*)d_in[0];
  const float* mask = (const float*)d_in[1];
  const float* lnw  = (const float*)d_in[2];
  const float* lnb  = (const float*)d_in[3];
  const float* w1   = (const float*)d_in[4];
  const float* w2   = (const float*)d_in[5];
  const float* wout = (const float*)d_in[6];
  const float* bout = (const float*)d_in[7];
  float* out = (float*)d_out;

  char* ws = (char*)d_ws;
  uint16_t* AF  = (uint16_t*)ws;                        // 1.5 MB
  uint16_t* BF  = (uint16_t*)(ws + 1572864);            // 1.5 MB
  uint16_t* W   = (uint16_t*)(ws + 3145728);            // 256 KB
  float* invn   = (float*)(ws + 3407872);               // 576 KB

  k_prep<<<NT, 256, 0, stream>>>(m, mask, lnw, lnb, w1, w2, AF, BF);
  k_misc<<<640, 256, 0, stream>>>(wout, mask, W, invn);

  (void)hipFuncSetAttribute(reinterpret_cast<const void*>(k_main),
                            hipFuncAttributeMaxDynamicSharedMemorySize, 81920);
  k_main<<<dim3(NT / 8, NT / 4), 512, 81920, stream>>>(AF, BF, W, bout, invn, out);
}